// Round 6
// baseline (191.003 us; speedup 1.0000x reference)
//
#include <hip/hip_runtime.h>
#include <math.h>

// EquiTritonModel: N=10000 nodes, E=160000 edges, D=32, H=16, NB=16.
// R5 -> R6 (gather latency-bound: VALUBusy 25%, 480k LDS bank conflicts):
//  - G1/G4 and T0/T1 stored TRANSPOSED ([in][out] -> [out][in]):
//    epilogue LDS reads become lane-consecutive (conflict-free), T-table
//    reads become 8x float4 per edge instead of 32x strided dword.
//  - zbuf layout [node][t][4] = (Q,Px,Py,Pz) per component: phase2 loads one
//    float4/lane instead of 4 strided dwords.
//  - gather: 128-thread blocks (2 nodes each, 5000 blocks) for residency
//    granularity; explicit next-edge prefetch (elist/coords/an) ahead of the
//    compute body.

namespace {
constexpr int   NATOMS   = 100;
constexpr int   CAP      = 64;
constexpr float PI_F     = 3.14159265358979323846f;
constexpr float INV4PI_F = 0.28209479177387814f;   // 1/sqrt(4*pi)
constexpr float SQRT3_F  = 1.7320508075688772f;
constexpr float CUT_F    = 6.0f;
constexpr float BASIS_C  = 2.3094010767585034f;    // sqrt(2/6)*sqrt(16)
constexpr float N0_F     = 0.17677669529663687f;   // 1/sqrt(32)
constexpr float K0_F = INV4PI_F * N0_F * 0.0625f;
constexpr float K1_F = SQRT3_F * INV4PI_F * N0_F * 0.0625f;
}

__device__ __forceinline__ float silu_fast(float x) {
  return x / (1.0f + __expf(-x));
}

__device__ __forceinline__ float block_reduce_sum(float v) {
  #pragma unroll
  for (int o = 32; o > 0; o >>= 1) v += __shfl_down(v, o, 64);
  __shared__ float ls[8];
  int lane = threadIdx.x & 63;
  int w    = threadIdx.x >> 6;
  if (lane == 0) ls[w] = v;
  __syncthreads();
  float s = 0.f;
  if (threadIdx.x == 0) {
    int nw = (blockDim.x + 63) >> 6;
    for (int i = 0; i < nw; ++i) s += ls[i];
  }
  return s;
}

// ---------------------------------------------------------------------------
// Precompute (TRANSPOSED outputs):
//  T0T/T1T[a][out t][in j]  (100x16x16)   G1T/G4T[in h][out j]... stored as
//  G*T[h*16 + j] so the gather epilogue reads lane-consecutive addresses.
// Thread t of block b: j_pre = t>>4 (gather input index), h_pre = t&15
// (gather output index). Writes [b*256 + h_pre*16 + j_pre].
// ---------------------------------------------------------------------------
__global__ void precompute_kernel(const float* __restrict__ atom_emb,
                                  const float* __restrict__ fc0_w2,
                                  const float* __restrict__ fc1_w2,
                                  const float* __restrict__ w_readout,
                                  float* __restrict__ T0T, float* __restrict__ T1T,
                                  float* __restrict__ G1T, float* __restrict__ G4T) {
  int b = blockIdx.x;
  int t = threadIdx.x;
  int j = t >> 4;     // input index (contracted with h0/z)
  int h = t & 15;     // output component
  int tidx = h * 16 + j;   // transposed position
  if (b < NATOMS) {
    float s0 = 0.f, s1 = 0.f;
    #pragma unroll
    for (int d = 0; d < 32; ++d) {
      float x = atom_emb[b * 32 + d];
      s0 = fmaf(x, fc0_w2[j * 1024 + d * 16 + h], s0);
      s1 = fmaf(x, fc0_w2[j * 1024 + 512 + d * 16 + h], s1);
    }
    T0T[b * 256 + tidx] = s0;
    T1T[b * 256 + tidx] = s1;
  } else {
    float g1 = 0.f, g4 = 0.f;
    #pragma unroll
    for (int k = 0; k < 16; ++k) {
      float r = w_readout[k];
      g1 = fmaf(fc1_w2[j * 1024 + h * 16 + k], r, g1);
      g4 = fmaf(fc1_w2[j * 1024 + 768 + h * 16 + k], r, g4);
    }
    // epilogue: o_j = sum_h G[j,h] v_h, reads ggs[h*16 + j]
    G1T[h * 16 + j] = g1;
    G4T[h * 16 + j] = g4;
  }
}

// ---------------------------------------------------------------------------
// Bucket by dst into fixed-capacity slots (stores SRC id).
// ---------------------------------------------------------------------------
__global__ void bucket_kernel(const int* __restrict__ ei,
                              int* __restrict__ cursor,
                              int* __restrict__ elist, int E) {
  int e = blockIdx.x * blockDim.x + threadIdx.x;
  if (e < E) {
    int d = ei[E + e];
    int pos = atomicAdd(&cursor[d], 1);
    if (pos < CAP) elist[d * CAP + pos] = ei[e];
  }
}

// ---------------------------------------------------------------------------
// Phase 1: 128-thread blocks, one wave per node (2 nodes/block), 4 groups x
// 16 lanes per wave. Lane t owns component t. T tables transposed: lane t
// loads its 16-float row as 4x float4. Epilogue: group 0 -> Q (G1), groups
// 1..3 -> Px/Py/Pz (G4); stored as zbuf[node*64 + t*4 + g].
// ---------------------------------------------------------------------------
__global__ void __launch_bounds__(128)
gather_kernel(const int* __restrict__ elist,
              const int* __restrict__ cursor,
              const float* __restrict__ coords,
              const int* __restrict__ an,
              const float* __restrict__ fc0_w1,
              const float* __restrict__ T0T,
              const float* __restrict__ T1T,
              const float* __restrict__ G1T,
              const float* __restrict__ G4T,
              const float* __restrict__ w_readout,
              float* __restrict__ zbuf,
              float* __restrict__ out,
              int N) {
  __shared__ float ggs[512];          // [0:256)=G1T, [256:512)=G4T
  {
    int tt = threadIdx.x;
    ggs[tt]       = G1T[tt];
    ggs[tt + 128] = G1T[tt + 128];
    ggs[tt + 256] = G4T[tt];
    ggs[tt + 384] = G4T[tt + 128];
  }
  __syncthreads();

  int wave = threadIdx.x >> 6;
  int lane = threadIdx.x & 63;
  int g    = lane >> 4;
  int t    = lane & 15;
  int base = lane & 48;
  int node = blockIdx.x * 2 + wave;
  bool valid = node < N;

  // per-lane column t of fc0_w1 (register-resident)
  float w0c[16];
  #pragma unroll
  for (int k = 0; k < 16; ++k) w0c[k] = fc0_w1[k * 16 + t];
  float rr = w_readout[t];

  float cnx = 0.f, cny = 0.f, cnz = 0.f;
  int cnt = 0;
  if (valid) {
    cnx = coords[3 * node + 0];
    cny = coords[3 * node + 1];
    cnz = coords[3 * node + 2];
    cnt = min(cursor[node], CAP);
  }

  const float angc = PI_F / CUT_F;
  float acc0 = 0.f, accx = 0.f, accy = 0.f, accz = 0.f;

  // prefetch first edge
  int s = (g < cnt) ? elist[node * CAP + g] : 0;
  float sx = coords[3 * s + 0];
  float sy = coords[3 * s + 1];
  float sz = coords[3 * s + 2];
  int   a  = an[s];

  for (int i = g; i < cnt; i += 4) {
    // prefetch next edge while computing current
    int inext = i + 4;
    int sn = (inext < cnt) ? elist[node * CAP + inext] : 0;
    float nsx = coords[3 * sn + 0];
    float nsy = coords[3 * sn + 1];
    float nsz = coords[3 * sn + 2];
    int   na  = an[sn];

    float vx = sx - cnx;
    float vy = sy - cny;
    float vz = sz - cnz;
    float dist = sqrtf(vx * vx + vy * vy + vz * vz);
    float inv  = 1.0f / fmaxf(dist, 1e-9f);
    float ux = vx * inv, uy = vy * inv, uz = vz * inv;
    float bc = (dist < CUT_F) ? (BASIS_C * inv) : 0.0f;

    // h0_t via sine recurrence (no cross-lane)
    float ang = angc * dist;
    float sc = __sinf(ang);
    float tw = 2.0f * __cosf(ang);
    float sp = 0.f, acc = 0.f;
    #pragma unroll
    for (int k = 0; k < 16; ++k) {
      acc = fmaf(sc, w0c[k], acc);
      float sn2 = fmaf(tw, sc, -sp);
      sp = sc; sc = sn2;
    }
    float h0t = silu_fast(acc * bc * 0.25f);

    // lane t's T rows (transposed layout, contiguous 64B): 8x float4
    const float4* t0 = (const float4*)(T0T + a * 256 + t * 16);
    const float4* t1 = (const float4*)(T1T + a * 256 + t * 16);
    float4 A0 = t0[0], A1 = t0[1], A2 = t0[2], A3 = t0[3];
    float4 B0 = t1[0], B1 = t1[1], B2 = t1[2], B3 = t1[3];
    float r0[16] = {A0.x,A0.y,A0.z,A0.w, A1.x,A1.y,A1.z,A1.w,
                    A2.x,A2.y,A2.z,A2.w, A3.x,A3.y,A3.z,A3.w};
    float r1[16] = {B0.x,B0.y,B0.z,B0.w, B1.x,B1.y,B1.z,B1.w,
                    B2.x,B2.y,B2.z,B2.w, B3.x,B3.y,B3.z,B3.w};

    float u0 = 0.f, u1 = 0.f;
    #pragma unroll
    for (int j = 0; j < 16; ++j) {
      float hj = __shfl(h0t, base + j, 64);
      u0 = fmaf(hj, r0[j], u0);
      u1 = fmaf(hj, r1[j], u1);
    }
    acc0 += u0;
    accx = fmaf(u1, ux, accx);
    accy = fmaf(u1, uy, accy);
    accz = fmaf(u1, uz, accz);

    s = sn; sx = nsx; sy = nsy; sz = nsz; a = na;
  }
  // full butterfly: every lane gets the 4-group totals for component t
  acc0 += __shfl_xor(acc0, 16, 64); acc0 += __shfl_xor(acc0, 32, 64);
  accx += __shfl_xor(accx, 16, 64); accx += __shfl_xor(accx, 32, 64);
  accy += __shfl_xor(accy, 16, 64); accy += __shfl_xor(accy, 32, 64);
  accz += __shfl_xor(accz, 16, 64); accz += __shfl_xor(accz, 32, 64);

  // epilogue: group 0 -> Q (G1), groups 1..3 -> P (G4); conflict-free LDS
  float srcv = (g == 0) ? acc0 * K0_F
                        : ((g == 1) ? accx : (g == 2) ? accy : accz) * K1_F;
  int tofs = (g == 0) ? 0 : 256;
  float o = 0.f;
  #pragma unroll
  for (int h = 0; h < 16; ++h) {
    float vh = __shfl(srcv, base + h, 64);
    o = fmaf(ggs[tofs + h * 16 + t], vh, o);
  }
  // layout: zbuf[node][t][g] -> float4 per component for phase2
  if (valid) zbuf[(size_t)node * 64 + t * 4 + g] = o;

  // node readout partial: 0.25 * sum_t z0_t * r_t (group 0 only)
  float p = (valid && g == 0) ? acc0 * K0_F * rr : 0.f;
  float tot = block_reduce_sum(p);
  if (threadIdx.x == 0) atomicAdd(out, tot * 0.25f);
}

// ---------------------------------------------------------------------------
// Phase 2: one 16-lane group per edge (grid-stride). Lane t owns j=t.
// c_e = (INV4PI*N0/64) * sum_j h1_j * (Q_j + P_j . u); zbuf read as float4.
// ---------------------------------------------------------------------------
__global__ void __launch_bounds__(256, 4)
phase2_kernel(const int* __restrict__ ei,
              const float* __restrict__ coords,
              const float* __restrict__ fc1_w1,
              const float* __restrict__ zbuf,
              float* __restrict__ out,
              int E) {
  int t = threadIdx.x & 15;
  float w1c[16];
  #pragma unroll
  for (int k = 0; k < 16; ++k) w1c[k] = fc1_w1[k * 16 + t];

  int gid = (blockIdx.x * blockDim.x + threadIdx.x) >> 4;
  int ngroups = (gridDim.x * blockDim.x) >> 4;
  const float angc = PI_F / CUT_F;

  float c = 0.f;
  for (int e = gid; e < E; e += ngroups) {
    int s = ei[e];
    int d = ei[E + e];
    float vx = coords[3 * s + 0] - coords[3 * d + 0];
    float vy = coords[3 * s + 1] - coords[3 * d + 1];
    float vz = coords[3 * s + 2] - coords[3 * d + 2];
    float dist = sqrtf(vx * vx + vy * vy + vz * vz);
    float inv  = 1.0f / fmaxf(dist, 1e-9f);
    float ux = vx * inv, uy = vy * inv, uz = vz * inv;
    float bc = (dist < CUT_F) ? (BASIS_C * inv) : 0.0f;

    float ang = angc * dist;
    float sc = __sinf(ang);
    float tw = 2.0f * __cosf(ang);
    float sp = 0.f, acc = 0.f;
    #pragma unroll
    for (int k = 0; k < 16; ++k) {
      acc = fmaf(sc, w1c[k], acc);
      float sn = fmaf(tw, sc, -sp);
      sp = sc; sc = sn;
    }
    float h1t = silu_fast(acc * bc * 0.25f);

    float4 z = ((const float4*)(zbuf + (size_t)s * 64))[t];
    c = fmaf(h1t, fmaf(z.y, ux, fmaf(z.z, uy, fmaf(z.w, uz, z.x))), c);
  }
  c *= INV4PI_F * N0_F * (1.0f / 64.0f);
  float tot = block_reduce_sum(c);
  if (threadIdx.x == 0) atomicAdd(out, tot);
}

extern "C" void kernel_launch(void* const* d_in, const int* in_sizes, int n_in,
                              void* d_out, int out_size, void* d_ws, size_t ws_size,
                              hipStream_t stream) {
  const int*   an        = (const int*)d_in[0];
  const float* coords    = (const float*)d_in[1];
  const int*   ei        = (const int*)d_in[2];
  const float* atom_emb  = (const float*)d_in[3];
  const float* fc0_w1    = (const float*)d_in[4];
  const float* fc0_w2    = (const float*)d_in[5];
  const float* fc1_w1    = (const float*)d_in[6];
  const float* fc1_w2    = (const float*)d_in[7];
  const float* w_readout = (const float*)d_in[8];

  int N = in_sizes[0];
  int E = in_sizes[2] / 2;

  float* ws   = (float*)d_ws;
  float* zbuf = ws;                         // N*64 floats
  float* T0T  = zbuf + (size_t)N * 64;      // 100*256
  float* T1T  = T0T + NATOMS * 256;         // 100*256
  float* G1T  = T1T + NATOMS * 256;         // 256
  float* G4T  = G1T + 256;                  // 256
  int*   cursor = (int*)(G4T + 256);        // N (count)
  int*   elist  = cursor + N;               // N*CAP
  float* out = (float*)d_out;

  hipMemsetAsync(cursor, 0, (size_t)N * sizeof(int), stream);
  hipMemsetAsync(out, 0, sizeof(float), stream);

  precompute_kernel<<<NATOMS + 1, 256, 0, stream>>>(
      atom_emb, fc0_w2, fc1_w2, w_readout, T0T, T1T, G1T, G4T);

  int blk = 256;
  bucket_kernel<<<(E + blk - 1) / blk, blk, 0, stream>>>(ei, cursor, elist, E);

  gather_kernel<<<(N + 1) / 2, 128, 0, stream>>>(
      elist, cursor, coords, an, fc0_w1, T0T, T1T, G1T, G4T, w_readout,
      zbuf, out, N);

  // 1024 blocks x 16 groups => 16384 groups, ~10 edges/group
  phase2_kernel<<<1024, blk, 0, stream>>>(ei, coords, fc1_w1, zbuf, out, E);
}

// Round 7
// 164.996 us; speedup vs baseline: 1.1576x; 1.1576x over previous
//
#include <hip/hip_runtime.h>
#include <math.h>

// EquiTritonModel: N=10000 nodes, E=160000 edges, D=32, H=16, NB=16.
// R6 -> R7: R6 regressed (gather 46->83us) -- float4 T-row loads were
// 64B-stride per lane (16 segments/instr) vs the perfectly-coalesced
// strided-dword pattern, and 128-thr blocks + prefetch lengthened the chain.
// R7 = R5 gather structure (256thr, 4 nodes/block, coalesced per-j dword
// T loads) + R6's conflict-free transposed ggs + float4 zbuf + NEW: 2-edge
// software pipelining per 16-lane group (doubles MLP; the per-edge chain is
// ~500cyc latency-bound with only ~4 iters/group). precompute+bucket fused.

namespace {
constexpr int   NATOMS   = 100;
constexpr int   CAP      = 64;
constexpr float PI_F     = 3.14159265358979323846f;
constexpr float INV4PI_F = 0.28209479177387814f;   // 1/sqrt(4*pi)
constexpr float SQRT3_F  = 1.7320508075688772f;
constexpr float CUT_F    = 6.0f;
constexpr float BASIS_C  = 2.3094010767585034f;    // sqrt(2/6)*sqrt(16)
constexpr float N0_F     = 0.17677669529663687f;   // 1/sqrt(32)
constexpr float K0_F = INV4PI_F * N0_F * 0.0625f;
constexpr float K1_F = SQRT3_F * INV4PI_F * N0_F * 0.0625f;
}

__device__ __forceinline__ float silu_fast(float x) {
  return x / (1.0f + __expf(-x));
}

__device__ __forceinline__ float block_reduce_sum(float v) {
  #pragma unroll
  for (int o = 32; o > 0; o >>= 1) v += __shfl_down(v, o, 64);
  __shared__ float ls[8];
  int lane = threadIdx.x & 63;
  int w    = threadIdx.x >> 6;
  if (lane == 0) ls[w] = v;
  __syncthreads();
  float s = 0.f;
  if (threadIdx.x == 0) {
    int nw = (blockDim.x + 63) >> 6;
    for (int i = 0; i < nw; ++i) s += ls[i];
  }
  return s;
}

// ---------------------------------------------------------------------------
// Fused setup: blocks [0, NATOMS] do precompute (T0/T1 in [j][t] layout,
// G1T/G4T transposed [comp][hidden]); blocks > NATOMS bucket edges by dst.
// ---------------------------------------------------------------------------
__global__ void setup_kernel(const float* __restrict__ atom_emb,
                             const float* __restrict__ fc0_w2,
                             const float* __restrict__ fc1_w2,
                             const float* __restrict__ w_readout,
                             const int* __restrict__ ei,
                             float* __restrict__ T0, float* __restrict__ T1,
                             float* __restrict__ G1T, float* __restrict__ G4T,
                             int* __restrict__ cursor, int* __restrict__ elist,
                             int E) {
  int b = blockIdx.x;
  int tt = threadIdx.x;
  if (b < NATOMS) {
    int j = tt >> 4;    // hidden (h0) index
    int h = tt & 15;    // H-component
    float s0 = 0.f, s1 = 0.f;
    #pragma unroll
    for (int d = 0; d < 32; ++d) {
      float x = atom_emb[b * 32 + d];
      s0 = fmaf(x, fc0_w2[j * 1024 + d * 16 + h], s0);
      s1 = fmaf(x, fc0_w2[j * 1024 + 512 + d * 16 + h], s1);
    }
    T0[b * 256 + tt] = s0;   // [j][h] layout -> gather reads stride-16 per j,
    T1[b * 256 + tt] = s1;   // coalesced across the 16 lanes (h)
  } else if (b == NATOMS) {
    int j = tt >> 4;    // hidden (h1) index
    int h = tt & 15;    // H-component
    float g1 = 0.f, g4 = 0.f;
    #pragma unroll
    for (int k = 0; k < 16; ++k) {
      float r = w_readout[k];
      g1 = fmaf(fc1_w2[j * 1024 + h * 16 + k], r, g1);
      g4 = fmaf(fc1_w2[j * 1024 + 768 + h * 16 + k], r, g4);
    }
    G1T[h * 16 + j] = g1;    // [comp][hidden]: epilogue reads lane-consecutive
    G4T[h * 16 + j] = g4;
  } else {
    int e = (b - NATOMS - 1) * blockDim.x + tt;
    if (e < E) {
      int d = ei[E + e];
      int pos = atomicAdd(&cursor[d], 1);
      if (pos < CAP) elist[d * CAP + pos] = ei[e];
    }
  }
}

// ---------------------------------------------------------------------------
// Phase 1: 256 threads = 4 waves = 4 nodes/block. Per wave: 4 groups x 16
// lanes; each group pipelines TWO edges (i, i+4) per iteration for MLP.
// Lane t owns component t. Epilogue: group 0 -> Q (G1), groups 1..3 ->
// Px/Py/Pz (G4); zbuf[node*64 + t*4 + g] (float4 per component for phase2).
// ---------------------------------------------------------------------------
__global__ void __launch_bounds__(256, 4)
gather_kernel(const int* __restrict__ elist,
              const int* __restrict__ cursor,
              const float* __restrict__ coords,
              const int* __restrict__ an,
              const float* __restrict__ fc0_w1,
              const float* __restrict__ T0,
              const float* __restrict__ T1,
              const float* __restrict__ G1T,
              const float* __restrict__ G4T,
              const float* __restrict__ w_readout,
              float* __restrict__ zbuf,
              float* __restrict__ out,
              int N) {
  __shared__ float ggs[512];          // [0:256)=G1T, [256:512)=G4T
  ggs[threadIdx.x]       = G1T[threadIdx.x];
  ggs[256 + threadIdx.x] = G4T[threadIdx.x];
  __syncthreads();

  int wave = threadIdx.x >> 6;
  int lane = threadIdx.x & 63;
  int g    = lane >> 4;
  int t    = lane & 15;
  int base = lane & 48;
  int node = blockIdx.x * 4 + wave;
  bool valid = node < N;

  float w0c[16];
  #pragma unroll
  for (int k = 0; k < 16; ++k) w0c[k] = fc0_w1[k * 16 + t];
  float rr = w_readout[t];

  float cnx = 0.f, cny = 0.f, cnz = 0.f;
  int cnt = 0;
  if (valid) {
    cnx = coords[3 * node + 0];
    cny = coords[3 * node + 1];
    cnz = coords[3 * node + 2];
    cnt = min(cursor[node], CAP);
  }
  const int* eb = elist + (size_t)(valid ? node : 0) * CAP;

  const float angc = PI_F / CUT_F;
  float acc0 = 0.f, accx = 0.f, accy = 0.f, accz = 0.f;

  for (int i = g; i < cnt; i += 8) {
    int iB = i + 4;
    bool hasB = iB < cnt;
    int sA = eb[i];
    int sB = hasB ? eb[iB] : sA;

    float pxA = coords[3 * sA + 0], pyA = coords[3 * sA + 1], pzA = coords[3 * sA + 2];
    float pxB = coords[3 * sB + 0], pyB = coords[3 * sB + 1], pzB = coords[3 * sB + 2];
    int aA = an[sA], aB = an[sB];

    float vxA = pxA - cnx, vyA = pyA - cny, vzA = pzA - cnz;
    float vxB = pxB - cnx, vyB = pyB - cny, vzB = pzB - cnz;
    float dA = sqrtf(vxA * vxA + vyA * vyA + vzA * vzA);
    float dB = sqrtf(vxB * vxB + vyB * vyB + vzB * vzB);
    float ivA = 1.0f / fmaxf(dA, 1e-9f);
    float ivB = 1.0f / fmaxf(dB, 1e-9f);
    float uxA = vxA * ivA, uyA = vyA * ivA, uzA = vzA * ivA;
    float uxB = vxB * ivB, uyB = vyB * ivB, uzB = vzB * ivB;
    float bcA = (dA < CUT_F) ? (BASIS_C * ivA) : 0.0f;
    float bcB = (dB < CUT_F) ? (BASIS_C * ivB) : 0.0f;

    // interleaved sine recurrences (two independent 16-deep chains)
    float angA = angc * dA, angB = angc * dB;
    float scA = __sinf(angA), twA = 2.0f * __cosf(angA), spA = 0.f, hA = 0.f;
    float scB = __sinf(angB), twB = 2.0f * __cosf(angB), spB = 0.f, hB = 0.f;
    #pragma unroll
    for (int k = 0; k < 16; ++k) {
      hA = fmaf(scA, w0c[k], hA);
      hB = fmaf(scB, w0c[k], hB);
      float snA = fmaf(twA, scA, -spA); spA = scA; scA = snA;
      float snB = fmaf(twB, scB, -spB); spB = scB; scB = snB;
    }
    float h0A = silu_fast(hA * bcA * 0.25f);
    float h0B = silu_fast(hB * bcB * 0.25f);

    // coalesced strided-dword T loads (lane t at base+4t), two edges in flight
    const float* t0A = T0 + aA * 256 + t;
    const float* t1A = T1 + aA * 256 + t;
    const float* t0B = T0 + aB * 256 + t;
    const float* t1B = T1 + aB * 256 + t;
    float u0A = 0.f, u1A = 0.f, u0B = 0.f, u1B = 0.f;
    #pragma unroll
    for (int j = 0; j < 16; ++j) {
      float hjA = __shfl(h0A, base + j, 64);
      float hjB = __shfl(h0B, base + j, 64);
      u0A = fmaf(hjA, t0A[j * 16], u0A);
      u1A = fmaf(hjA, t1A[j * 16], u1A);
      u0B = fmaf(hjB, t0B[j * 16], u0B);
      u1B = fmaf(hjB, t1B[j * 16], u1B);
    }
    float mB = hasB ? 1.0f : 0.0f;
    acc0 += u0A + mB * u0B;
    accx = fmaf(u1A, uxA, fmaf(mB * u1B, uxB, accx));
    accy = fmaf(u1A, uyA, fmaf(mB * u1B, uyB, accy));
    accz = fmaf(u1A, uzA, fmaf(mB * u1B, uzB, accz));
  }

  // full butterfly: every lane gets the 4-group totals for component t
  acc0 += __shfl_xor(acc0, 16, 64); acc0 += __shfl_xor(acc0, 32, 64);
  accx += __shfl_xor(accx, 16, 64); accx += __shfl_xor(accx, 32, 64);
  accy += __shfl_xor(accy, 16, 64); accy += __shfl_xor(accy, 32, 64);
  accz += __shfl_xor(accz, 16, 64); accz += __shfl_xor(accz, 32, 64);

  // epilogue: group 0 -> Q (G1), groups 1..3 -> P (G4); conflict-free LDS
  float srcv = (g == 0) ? acc0 * K0_F
                        : ((g == 1) ? accx : (g == 2) ? accy : accz) * K1_F;
  int tofs = (g == 0) ? 0 : 256;
  float o = 0.f;
  #pragma unroll
  for (int h = 0; h < 16; ++h) {
    float vh = __shfl(srcv, base + h, 64);
    o = fmaf(ggs[tofs + h * 16 + t], vh, o);
  }
  if (valid) zbuf[(size_t)node * 64 + t * 4 + g] = o;

  // node readout partial: 0.25 * sum_t z0_t * r_t (group 0 only)
  float p = (valid && g == 0) ? acc0 * K0_F * rr : 0.f;
  float tot = block_reduce_sum(p);
  if (threadIdx.x == 0) atomicAdd(out, tot * 0.25f);
}

// ---------------------------------------------------------------------------
// Phase 2: one 16-lane group per edge (grid-stride). Lane t owns j=t.
// c_e = (INV4PI*N0/64) * sum_j h1_j * (Q_j + P_j . u); zbuf read as float4.
// ---------------------------------------------------------------------------
__global__ void __launch_bounds__(256, 4)
phase2_kernel(const int* __restrict__ ei,
              const float* __restrict__ coords,
              const float* __restrict__ fc1_w1,
              const float* __restrict__ zbuf,
              float* __restrict__ out,
              int E) {
  int t = threadIdx.x & 15;
  float w1c[16];
  #pragma unroll
  for (int k = 0; k < 16; ++k) w1c[k] = fc1_w1[k * 16 + t];

  int gid = (blockIdx.x * blockDim.x + threadIdx.x) >> 4;
  int ngroups = (gridDim.x * blockDim.x) >> 4;
  const float angc = PI_F / CUT_F;

  float c = 0.f;
  for (int e = gid; e < E; e += ngroups) {
    int s = ei[e];
    int d = ei[E + e];
    float vx = coords[3 * s + 0] - coords[3 * d + 0];
    float vy = coords[3 * s + 1] - coords[3 * d + 1];
    float vz = coords[3 * s + 2] - coords[3 * d + 2];
    float dist = sqrtf(vx * vx + vy * vy + vz * vz);
    float inv  = 1.0f / fmaxf(dist, 1e-9f);
    float ux = vx * inv, uy = vy * inv, uz = vz * inv;
    float bc = (dist < CUT_F) ? (BASIS_C * inv) : 0.0f;

    float ang = angc * dist;
    float sc = __sinf(ang);
    float tw = 2.0f * __cosf(ang);
    float sp = 0.f, acc = 0.f;
    #pragma unroll
    for (int k = 0; k < 16; ++k) {
      acc = fmaf(sc, w1c[k], acc);
      float sn = fmaf(tw, sc, -sp);
      sp = sc; sc = sn;
    }
    float h1t = silu_fast(acc * bc * 0.25f);

    float4 z = ((const float4*)(zbuf + (size_t)s * 64))[t];
    c = fmaf(h1t, fmaf(z.y, ux, fmaf(z.z, uy, fmaf(z.w, uz, z.x))), c);
  }
  c *= INV4PI_F * N0_F * (1.0f / 64.0f);
  float tot = block_reduce_sum(c);
  if (threadIdx.x == 0) atomicAdd(out, tot);
}

extern "C" void kernel_launch(void* const* d_in, const int* in_sizes, int n_in,
                              void* d_out, int out_size, void* d_ws, size_t ws_size,
                              hipStream_t stream) {
  const int*   an        = (const int*)d_in[0];
  const float* coords    = (const float*)d_in[1];
  const int*   ei        = (const int*)d_in[2];
  const float* atom_emb  = (const float*)d_in[3];
  const float* fc0_w1    = (const float*)d_in[4];
  const float* fc0_w2    = (const float*)d_in[5];
  const float* fc1_w1    = (const float*)d_in[6];
  const float* fc1_w2    = (const float*)d_in[7];
  const float* w_readout = (const float*)d_in[8];

  int N = in_sizes[0];
  int E = in_sizes[2] / 2;

  float* ws   = (float*)d_ws;
  float* zbuf = ws;                         // N*64 floats
  float* T0   = zbuf + (size_t)N * 64;      // 100*256
  float* T1   = T0 + NATOMS * 256;          // 100*256
  float* G1T  = T1 + NATOMS * 256;          // 256
  float* G4T  = G1T + 256;                  // 256
  int*   cursor = (int*)(G4T + 256);        // N (count)
  int*   elist  = cursor + N;               // N*CAP
  float* out = (float*)d_out;

  hipMemsetAsync(cursor, 0, (size_t)N * sizeof(int), stream);
  hipMemsetAsync(out, 0, sizeof(float), stream);

  int blk = 256;
  int ebkts = (E + blk - 1) / blk;
  setup_kernel<<<NATOMS + 1 + ebkts, blk, 0, stream>>>(
      atom_emb, fc0_w2, fc1_w2, w_readout, ei,
      T0, T1, G1T, G4T, cursor, elist, E);

  gather_kernel<<<(N + 3) / 4, blk, 0, stream>>>(
      elist, cursor, coords, an, fc0_w1, T0, T1, G1T, G4T, w_readout,
      zbuf, out, N);

  // 2048 blocks x 16 groups => 32768 groups, ~5 edges/group
  phase2_kernel<<<2048, blk, 0, stream>>>(ei, coords, fc1_w1, zbuf, out, E);
}